// Round 1
// baseline (69.669 us; speedup 1.0000x reference)
//
#include <hip/hip_runtime.h>

namespace {

constexpr int NM    = 64;
constexpr int INF   = 256;
constexpr int OUTF  = 256;
constexpr int BATCH = 8192;
constexpr int CHUNK = 2048;   // samples scanned per workgroup
constexpr int SB    = 32;     // sample batch staged in LDS
constexpr int SH    = SB / 2; // samples per thread (two sample-halves of the block)

// Grid: (model m, chunk c, output-half oh). Block: 256 threads.
// Threads 0..127 handle sample-half 0, threads 128..255 sample-half 1.
// Each thread owns ONE output feature o = oh*128 + (tid&127) and SH samples.
__global__ __launch_bounds__(256, 2) void mml_kernel(
    const float* __restrict__ x,      // [BATCH][INF]
    const int*   __restrict__ idx,    // [BATCH]
    const float* __restrict__ w,      // [NM][OUTF][INF]
    const float* __restrict__ bias,   // [NM][OUTF]
    float*       __restrict__ out)    // [BATCH][OUTF]
{
  __shared__ int   s_list[CHUNK];
  __shared__ int   s_cnt;
  __shared__ float xs[SB][INF];

  const int m     = blockIdx.x;
  const int cbase = blockIdx.y * CHUNK;
  const int oh    = blockIdx.z;
  const int tid   = threadIdx.x;

  if (tid == 0) s_cnt = 0;
  __syncthreads();

  // Phase A: select samples in this chunk belonging to model m.
  for (int i = tid; i < CHUNK; i += 256) {
    if (idx[cbase + i] == m) {
      s_list[atomicAdd(&s_cnt, 1)] = cbase + i;
    }
  }
  __syncthreads();
  const int n = s_cnt;
  if (n == 0) return;

  const int o     = oh * 128 + (tid & 127);
  const int shalf = tid >> 7;
  const float4* __restrict__ wrow =
      reinterpret_cast<const float4*>(w + ((size_t)m * OUTF + o) * INF);
  const float bv = bias[m * OUTF + o];

  for (int s0 = 0; s0 < n; s0 += SB) {
    const int nb = min(SB, n - s0);

    __syncthreads();  // protect xs from previous batch's readers
    // Stage nb x-rows into LDS; 4 rows per iteration, 64B-aligned float4 loads.
    for (int r0 = 0; r0 < nb; r0 += 4) {
      const int r = r0 + (tid >> 6);
      if (r < nb) {
        const float4* src =
            reinterpret_cast<const float4*>(x + (size_t)s_list[s0 + r] * INF);
        reinterpret_cast<float4*>(xs[r])[tid & 63] = src[tid & 63];
      }
    }
    __syncthreads();

    float acc[SH];
#pragma unroll
    for (int s = 0; s < SH; ++s) acc[s] = 0.f;

    const int sb = shalf * SH;

#pragma unroll 4
    for (int k = 0; k < INF / 4; ++k) {
      const float4 wv = wrow[k];
#pragma unroll
      for (int s = 0; s < SH; ++s) {
        const float4 xv = *reinterpret_cast<const float4*>(&xs[sb + s][4 * k]);
        acc[s] = fmaf(wv.x, xv.x, acc[s]);
        acc[s] = fmaf(wv.y, xv.y, acc[s]);
        acc[s] = fmaf(wv.z, xv.z, acc[s]);
        acc[s] = fmaf(wv.w, xv.w, acc[s]);
      }
    }

    // Epilogue: only write real samples (un-staged tail rows were computed on
    // stale LDS but are never written).
    const int smax = min(SH, nb - sb);
    for (int s = 0; s < smax; ++s) {
      out[(size_t)s_list[s0 + sb + s] * OUTF + o] = acc[s] + bv;
    }
  }
}

}  // namespace

extern "C" void kernel_launch(void* const* d_in, const int* in_sizes, int n_in,
                              void* d_out, int out_size, void* d_ws, size_t ws_size,
                              hipStream_t stream) {
  const float* x    = (const float*)d_in[0];
  const int*   idx  = (const int*)d_in[1];
  const float* w    = (const float*)d_in[2];
  const float* bias = (const float*)d_in[3];
  float*       out  = (float*)d_out;

  dim3 grid(NM, BATCH / CHUNK, 2);
  hipLaunchKernelGGL(mml_kernel, grid, dim3(256), 0, stream,
                     x, idx, w, bias, out);
}

// Round 2
// 61.767 us; speedup vs baseline: 1.1279x; 1.1279x over previous
//
#include <hip/hip_runtime.h>

namespace {

constexpr int NM    = 64;
constexpr int INF   = 256;
constexpr int OUTF  = 256;
constexpr int BATCH = 8192;
constexpr int MAXN  = 512;          // per-model bucket capacity (n_m ~ Poisson(128), 512 is >30 sigma)
constexpr int TS    = 32;           // samples per tile
constexpr int MAXT  = MAXN / TS;    // 16 tiles max per model
constexpr int XSTR  = 36;           // LDS k-row stride in floats (32 samples + 4 pad)

// ---- Kernel 1: bucket samples by model id. Slot order within a bucket is
// nondeterministic (atomic race) but each sample's OUTPUT is computed
// identically regardless of slot -> output deterministic.
__global__ void scatter_kernel(const int* __restrict__ idx,
                               int* __restrict__ cnt,
                               unsigned short* __restrict__ bucket) {
  const int i = blockIdx.x * 256 + threadIdx.x;
  if (i < BATCH) {
    const int m = idx[i];
    const int pos = atomicAdd(&cnt[m], 1);
    if (pos < MAXN) bucket[m * MAXN + pos] = (unsigned short)i;
  }
}

// ---- Kernel 2: per (model, sample-tile, output-half) GEMM tile.
// 256 threads: sg = tid&7 (4-sample group), og = tid>>3 (4-output group).
// Each thread: 4 outputs x 4 samples = 16 f32 accumulators.
// x-tile staged ONCE, k-major, in LDS; k-loop is barrier-free.
__global__ __launch_bounds__(256, 3) void gemm_kernel(
    const float* __restrict__ x,        // [BATCH][INF]
    const float* __restrict__ w,        // [NM][OUTF][INF]
    const float* __restrict__ bias,     // [NM][OUTF]
    const int* __restrict__ cnt,        // [NM]
    const unsigned short* __restrict__ bucket,  // [NM][MAXN]
    float* __restrict__ out)            // [BATCH][OUTF]
{
  const int m = blockIdx.x;
  const int t = blockIdx.y;
  const int h = blockIdx.z;
  const int n = min(cnt[m], MAXN);
  const int base = t * TS;
  if (base >= n) return;
  const int nb = min(TS, n - base);

  __shared__ float xs[256 * XSTR];   // [k][sample], stride 36 -> conflict-free
  __shared__ int   sid[TS];

  const int tid = threadIdx.x;

  // --- stage x tile transposed (k-major). r = sample row, c = 32-float chunk.
  {
    const int r = tid & 31;
    const int c = tid >> 5;          // 0..7
    if (r < nb) {
      const int id = bucket[m * MAXN + base + r];
      if (c == 0) sid[r] = id;
      const float4* __restrict__ xrow =
          reinterpret_cast<const float4*>(x + (size_t)id * INF);
#pragma unroll
      for (int j = 0; j < 8; ++j) {
        const float4 v = xrow[c * 8 + j];
        const int k0 = c * 32 + j * 4;
        xs[(k0 + 0) * XSTR + r] = v.x;
        xs[(k0 + 1) * XSTR + r] = v.y;
        xs[(k0 + 2) * XSTR + r] = v.z;
        xs[(k0 + 3) * XSTR + r] = v.w;
      }
    }
  }
  __syncthreads();

  const int sg = tid & 7;            // sample group: samples sg*4 .. sg*4+3
  const int og = tid >> 3;           // output group: outputs o0 .. o0+3
  const int o0 = h * 128 + og * 4;

  const float4* __restrict__ w4 =
      reinterpret_cast<const float4*>(w + ((size_t)m * OUTF + o0) * INF);
  // w4[oj*64 + k4] = w[m][o0+oj][4*k4 .. 4*k4+3]

  float acc[4][4];
#pragma unroll
  for (int a = 0; a < 4; ++a)
#pragma unroll
    for (int b = 0; b < 4; ++b) acc[a][b] = 0.f;

  const float* __restrict__ xp = &xs[sg * 4];

#pragma unroll 2
  for (int k4 = 0; k4 < INF / 4; ++k4) {
    const float4 wv0 = w4[0 * 64 + k4];
    const float4 wv1 = w4[1 * 64 + k4];
    const float4 wv2 = w4[2 * 64 + k4];
    const float4 wv3 = w4[3 * 64 + k4];
    const float4 xv0 = *reinterpret_cast<const float4*>(xp + (4 * k4 + 0) * XSTR);
    const float4 xv1 = *reinterpret_cast<const float4*>(xp + (4 * k4 + 1) * XSTR);
    const float4 xv2 = *reinterpret_cast<const float4*>(xp + (4 * k4 + 2) * XSTR);
    const float4 xv3 = *reinterpret_cast<const float4*>(xp + (4 * k4 + 3) * XSTR);

#define FMA_E(E, XV)                                   \
    acc[0][0] = fmaf(wv0.E, XV.x, acc[0][0]);          \
    acc[0][1] = fmaf(wv0.E, XV.y, acc[0][1]);          \
    acc[0][2] = fmaf(wv0.E, XV.z, acc[0][2]);          \
    acc[0][3] = fmaf(wv0.E, XV.w, acc[0][3]);          \
    acc[1][0] = fmaf(wv1.E, XV.x, acc[1][0]);          \
    acc[1][1] = fmaf(wv1.E, XV.y, acc[1][1]);          \
    acc[1][2] = fmaf(wv1.E, XV.z, acc[1][2]);          \
    acc[1][3] = fmaf(wv1.E, XV.w, acc[1][3]);          \
    acc[2][0] = fmaf(wv2.E, XV.x, acc[2][0]);          \
    acc[2][1] = fmaf(wv2.E, XV.y, acc[2][1]);          \
    acc[2][2] = fmaf(wv2.E, XV.z, acc[2][2]);          \
    acc[2][3] = fmaf(wv2.E, XV.w, acc[2][3]);          \
    acc[3][0] = fmaf(wv3.E, XV.x, acc[3][0]);          \
    acc[3][1] = fmaf(wv3.E, XV.y, acc[3][1]);          \
    acc[3][2] = fmaf(wv3.E, XV.z, acc[3][2]);          \
    acc[3][3] = fmaf(wv3.E, XV.w, acc[3][3]);

    FMA_E(x, xv0)
    FMA_E(y, xv1)
    FMA_E(z, xv2)
    FMA_E(w, xv3)
#undef FMA_E
  }

  // --- epilogue: bias + store. 4 consecutive outputs -> one float4 per sample.
  const float4 bv = *reinterpret_cast<const float4*>(bias + m * OUTF + o0);
#pragma unroll
  for (int sj = 0; sj < 4; ++sj) {
    const int s = sg * 4 + sj;
    if (s < nb) {
      float4 r;
      r.x = acc[0][sj] + bv.x;
      r.y = acc[1][sj] + bv.y;
      r.z = acc[2][sj] + bv.z;
      r.w = acc[3][sj] + bv.w;
      *reinterpret_cast<float4*>(out + (size_t)sid[s] * OUTF + o0) = r;
    }
  }
}

}  // namespace

extern "C" void kernel_launch(void* const* d_in, const int* in_sizes, int n_in,
                              void* d_out, int out_size, void* d_ws, size_t ws_size,
                              hipStream_t stream) {
  const float* x    = (const float*)d_in[0];
  const int*   idx  = (const int*)d_in[1];
  const float* w    = (const float*)d_in[2];
  const float* bias = (const float*)d_in[3];
  float*       out  = (float*)d_out;

  int* cnt = (int*)d_ws;                                     // 64 ints
  unsigned short* bucket = (unsigned short*)((char*)d_ws + 256);  // 64*512 u16

  hipMemsetAsync(cnt, 0, NM * sizeof(int), stream);
  hipLaunchKernelGGL(scatter_kernel, dim3(BATCH / 256), dim3(256), 0, stream,
                     idx, cnt, bucket);
  hipLaunchKernelGGL(gemm_kernel, dim3(NM, MAXT, 2), dim3(256), 0, stream,
                     x, w, bias, cnt, bucket, out);
}

// Round 4
// 44.449 us; speedup vs baseline: 1.5674x; 1.3896x over previous
//
#include <hip/hip_runtime.h>

typedef __attribute__((ext_vector_type(8))) short short8;
typedef __attribute__((ext_vector_type(4))) float f32x4;

namespace {

constexpr int NM    = 64;
constexpr int INF   = 256;
constexpr int OUTF  = 256;
constexpr int BATCH = 8192;
constexpr int MAXN  = 512;   // bucket capacity (n_m ~ Binom(8192,1/64): mean 128, sd 11)
constexpr int TS    = 32;    // samples per tile
constexpr int MAXT  = 10;    // covers n_m <= 320 (>17 sigma)
constexpr int OQ    = 64;    // outputs per block

// ---- Kernel 1 (R2-proven): global-atomic bucket scatter. Slot order is
// nondeterministic but each sample's output value is slot-independent.
__global__ void scatter_kernel(const int* __restrict__ idx,
                               int* __restrict__ cnt,
                               unsigned short* __restrict__ bucket) {
  const int i = blockIdx.x * 256 + threadIdx.x;
  if (i < BATCH) {
    const int m = idx[i];
    const int pos = atomicAdd(&cnt[m], 1);
    if (pos < MAXN) bucket[m * MAXN + pos] = (unsigned short)i;
  }
}

// RNE f32 -> bf16, software (no asm). Inputs are finite.
__device__ inline unsigned short bf16_rne(float f) {
  const unsigned u = __float_as_uint(f);
  return (unsigned short)((u + 0x7FFFu + ((u >> 16) & 1u)) >> 16);
}

// Single source of truth for the LDS layout of a [rows][256] bf16 tile
// (512 B per row): element (row, k) lives at byte swz(row, 2*k).
// XOR of bits 4-6 by (row&7) kills the stride-512B b128 bank conflict; it
// preserves 8B/16B alignment since it only touches bits 4-6.
__device__ inline int swz(int row, int byte_in_row) {
  return row * 512 + (byte_in_row ^ ((row & 7) << 4));
}

// Pack a float4 (4 consecutive k) to 4 bf16 and store at chunk index
// (chunk = k/4) of `row`.
__device__ inline void stage4(char* lds, int row, int chunk, float4 v) {
  union { unsigned short s[4]; uint2 u; } p;
  p.s[0] = bf16_rne(v.x);
  p.s[1] = bf16_rne(v.y);
  p.s[2] = bf16_rne(v.z);
  p.s[3] = bf16_rne(v.w);
  *reinterpret_cast<uint2*>(lds + swz(row, chunk * 8)) = p.u;
}

// ---- Kernel 2: per (model, 32-sample tile, 64-output quarter) MFMA tile.
// 4 waves; wave wid owns outputs [h*64 + wid*16, +16).
// mfma_f32_16x16x32_bf16 (m89/m92-verified usage):
//   A frag: row = l&15 (sample slot), claimed k = 32*kc + 8*(l>>4) + j
//   B frag: col = l&15 (output),      claimed k = same formula  (k-perm cancels)
//   D:      col = l&15, row = 4*(l>>4) + reg
__global__ __launch_bounds__(256) void gemm_kernel(
    const float* __restrict__ x,               // [BATCH][INF]
    const float* __restrict__ w,               // [NM][OUTF][INF]
    const float* __restrict__ bias,            // [NM][OUTF]
    const int* __restrict__ cnt,               // [NM]
    const unsigned short* __restrict__ bucket, // [NM][MAXN]
    float* __restrict__ out)                   // [BATCH][OUTF]
{
  const int m = blockIdx.x;
  const int t = blockIdx.y;
  const int h = blockIdx.z;
  const int n = min(cnt[m], MAXN);
  const int base = t * TS;
  if (base >= n) return;
  const int nb = min(TS, n - base);

  __shared__ __align__(16) char xs[TS * 512];  // 16 KB: [32][256] bf16, swizzled
  __shared__ __align__(16) char ws[OQ * 512];  // 32 KB: [64][256] bf16, swizzled
  __shared__ int sid[TS];

  const int tid = threadIdx.x;

  // --- stage x tile: row r = tid>>3 (0..31), c = tid&7, chunks c*8+j.
  {
    const int r = tid >> 3;
    const int c = tid & 7;
    if (r < nb) {
      const int id = bucket[m * MAXN + base + r];
      if (c == 0) sid[r] = id;
      const float4* __restrict__ xrow =
          reinterpret_cast<const float4*>(x + (size_t)id * INF);
#pragma unroll
      for (int j = 0; j < 8; ++j) stage4(xs, r, c * 8 + j, xrow[c * 8 + j]);
    } else {
      const float4 z = make_float4(0.f, 0.f, 0.f, 0.f);
#pragma unroll
      for (int j = 0; j < 8; ++j) stage4(xs, r, c * 8 + j, z);
    }
  }

  // --- stage w quarter: row r = tid>>2 (0..63), q = tid&3, chunks q*16+j.
  {
    const int r = tid >> 2;
    const int q = tid & 3;
    const float4* __restrict__ wrow = reinterpret_cast<const float4*>(
        w + ((size_t)m * OUTF + h * OQ + r) * INF);
#pragma unroll
    for (int j = 0; j < 16; ++j) stage4(ws, r, q * 16 + j, wrow[q * 16 + j]);
  }
  __syncthreads();

  const int wid = tid >> 6;
  const int l   = tid & 63;
  const int lr  = l & 15;
  const int lg  = l >> 4;

  f32x4 acc0 = {0.f, 0.f, 0.f, 0.f};
  f32x4 acc1 = {0.f, 0.f, 0.f, 0.f};

#pragma unroll
  for (int kc = 0; kc < 8; ++kc) {
    const int kb = kc * 64 + lg * 16;  // byte offset of this lane's 8 bf16
    const short8 a0 = *reinterpret_cast<const short8*>(xs + swz(lr, kb));
    const short8 a1 = *reinterpret_cast<const short8*>(xs + swz(16 + lr, kb));
    const short8 b  = *reinterpret_cast<const short8*>(ws + swz(wid * 16 + lr, kb));
    acc0 = __builtin_amdgcn_mfma_f32_16x16x32_bf16(a0, b, acc0, 0, 0, 0);
    acc1 = __builtin_amdgcn_mfma_f32_16x16x32_bf16(a1, b, acc1, 0, 0, 0);
  }

  // --- epilogue: bias + guarded scatter-store.
  const int o = h * OQ + wid * 16 + lr;
  const float bv = bias[m * OUTF + o];
#pragma unroll
  for (int j = 0; j < 4; ++j) {
    const int s0 = lg * 4 + j;
    if (s0 < nb) out[(size_t)sid[s0] * OUTF + o] = acc0[j] + bv;
    const int s1 = 16 + lg * 4 + j;
    if (s1 < nb) out[(size_t)sid[s1] * OUTF + o] = acc1[j] + bv;
  }
}

}  // namespace

extern "C" void kernel_launch(void* const* d_in, const int* in_sizes, int n_in,
                              void* d_out, int out_size, void* d_ws, size_t ws_size,
                              hipStream_t stream) {
  const float* x    = (const float*)d_in[0];
  const int*   idx  = (const int*)d_in[1];
  const float* w    = (const float*)d_in[2];
  const float* bias = (const float*)d_in[3];
  float*       out  = (float*)d_out;

  int* cnt = (int*)d_ws;                                          // 64 ints
  unsigned short* bucket = (unsigned short*)((char*)d_ws + 256);  // 64*512 u16

  hipMemsetAsync(cnt, 0, NM * sizeof(int), stream);
  hipLaunchKernelGGL(scatter_kernel, dim3(BATCH / 256), dim3(256), 0, stream,
                     idx, cnt, bucket);
  hipLaunchKernelGGL(gemm_kernel, dim3(NM, MAXT, 4), dim3(256), 0, stream,
                     x, w, bias, cnt, bucket, out);
}

// Round 5
// 33.614 us; speedup vs baseline: 2.0726x; 1.3223x over previous
//
#include <hip/hip_runtime.h>

typedef __attribute__((ext_vector_type(8))) short short8;
typedef __attribute__((ext_vector_type(4))) float f32x4;

namespace {

constexpr int NM    = 64;
constexpr int INF   = 256;
constexpr int OUTF  = 256;
constexpr int BATCH = 8192;
constexpr int MAXN  = 512;   // bucket capacity (n_m ~ Binom(8192,1/64): mean 128, sd 11)
constexpr int TS    = 32;    // samples per tile
constexpr int MAXT  = 10;    // covers n_m <= 320 (>17 sigma)
constexpr int OQ    = 64;    // outputs per block

// ---- Kernel 1: per-model scan scatter. Block m scans all indices for model m
// into its bucket via an LDS counter, then writes cnt[m] itself -> NO memset
// dispatch needed (the 256-byte fillBuffer was 41 us of the 44 us R4 time).
// Slot order within a bucket is scheduling-dependent, but each sample's output
// value is slot-independent -> output deterministic.
__global__ void scatter_kernel(const int* __restrict__ idx,
                               int* __restrict__ cnt,
                               unsigned short* __restrict__ bucket) {
  __shared__ int lcnt;
  const int m = blockIdx.x;
  if (threadIdx.x == 0) lcnt = 0;
  __syncthreads();
  for (int i = threadIdx.x; i < BATCH; i += 256) {
    if (idx[i] == m) {
      const int p = atomicAdd(&lcnt, 1);
      if (p < MAXN) bucket[m * MAXN + p] = (unsigned short)i;
    }
  }
  __syncthreads();
  if (threadIdx.x == 0) cnt[m] = min(lcnt, MAXN);
}

// RNE f32 -> bf16, software (no asm). Inputs are finite.
__device__ inline unsigned short bf16_rne(float f) {
  const unsigned u = __float_as_uint(f);
  return (unsigned short)((u + 0x7FFFu + ((u >> 16) & 1u)) >> 16);
}

// Single source of truth for the LDS layout of a [rows][256] bf16 tile
// (512 B per row): element (row, k) lives at byte swz(row, 2*k).
// XOR of bits 4-6 by (row&7) kills the stride-512B b128 bank conflict; it
// preserves 8B/16B alignment since it only touches bits 4-6.
__device__ inline int swz(int row, int byte_in_row) {
  return row * 512 + (byte_in_row ^ ((row & 7) << 4));
}

// Pack a float4 (4 consecutive k) to 4 bf16 and store at chunk index
// (chunk = k/4) of `row`.
__device__ inline void stage4(char* lds, int row, int chunk, float4 v) {
  union { unsigned short s[4]; uint2 u; } p;
  p.s[0] = bf16_rne(v.x);
  p.s[1] = bf16_rne(v.y);
  p.s[2] = bf16_rne(v.z);
  p.s[3] = bf16_rne(v.w);
  *reinterpret_cast<uint2*>(lds + swz(row, chunk * 8)) = p.u;
}

// ---- Kernel 2 (R4-proven, unchanged): per (model, 32-sample tile,
// 64-output quarter) MFMA tile. 4 waves; wave wid owns outputs
// [h*64 + wid*16, +16). mfma_f32_16x16x32_bf16 (m89/m92-verified usage).
__global__ __launch_bounds__(256) void gemm_kernel(
    const float* __restrict__ x,               // [BATCH][INF]
    const float* __restrict__ w,               // [NM][OUTF][INF]
    const float* __restrict__ bias,            // [NM][OUTF]
    const int* __restrict__ cnt,               // [NM]
    const unsigned short* __restrict__ bucket, // [NM][MAXN]
    float* __restrict__ out)                   // [BATCH][OUTF]
{
  const int m = blockIdx.x;
  const int t = blockIdx.y;
  const int h = blockIdx.z;
  const int n = min(cnt[m], MAXN);
  const int base = t * TS;
  if (base >= n) return;
  const int nb = min(TS, n - base);

  __shared__ __align__(16) char xs[TS * 512];  // 16 KB: [32][256] bf16, swizzled
  __shared__ __align__(16) char ws[OQ * 512];  // 32 KB: [64][256] bf16, swizzled
  __shared__ int sid[TS];

  const int tid = threadIdx.x;

  // --- stage x tile: row r = tid>>3 (0..31), c = tid&7, chunks c*8+j.
  {
    const int r = tid >> 3;
    const int c = tid & 7;
    if (r < nb) {
      const int id = bucket[m * MAXN + base + r];
      if (c == 0) sid[r] = id;
      const float4* __restrict__ xrow =
          reinterpret_cast<const float4*>(x + (size_t)id * INF);
#pragma unroll
      for (int j = 0; j < 8; ++j) stage4(xs, r, c * 8 + j, xrow[c * 8 + j]);
    } else {
      const float4 z = make_float4(0.f, 0.f, 0.f, 0.f);
#pragma unroll
      for (int j = 0; j < 8; ++j) stage4(xs, r, c * 8 + j, z);
    }
  }

  // --- stage w quarter: row r = tid>>2 (0..63), q = tid&3, chunks q*16+j.
  {
    const int r = tid >> 2;
    const int q = tid & 3;
    const float4* __restrict__ wrow = reinterpret_cast<const float4*>(
        w + ((size_t)m * OUTF + h * OQ + r) * INF);
#pragma unroll
    for (int j = 0; j < 16; ++j) stage4(ws, r, q * 16 + j, wrow[q * 16 + j]);
  }
  __syncthreads();

  const int wid = tid >> 6;
  const int l   = tid & 63;
  const int lr  = l & 15;
  const int lg  = l >> 4;

  f32x4 acc0 = {0.f, 0.f, 0.f, 0.f};
  f32x4 acc1 = {0.f, 0.f, 0.f, 0.f};

#pragma unroll
  for (int kc = 0; kc < 8; ++kc) {
    const int kb = kc * 64 + lg * 16;  // byte offset of this lane's 8 bf16
    const short8 a0 = *reinterpret_cast<const short8*>(xs + swz(lr, kb));
    const short8 a1 = *reinterpret_cast<const short8*>(xs + swz(16 + lr, kb));
    const short8 b  = *reinterpret_cast<const short8*>(ws + swz(wid * 16 + lr, kb));
    acc0 = __builtin_amdgcn_mfma_f32_16x16x32_bf16(a0, b, acc0, 0, 0, 0);
    acc1 = __builtin_amdgcn_mfma_f32_16x16x32_bf16(a1, b, acc1, 0, 0, 0);
  }

  // --- epilogue: bias + guarded scatter-store.
  const int o = h * OQ + wid * 16 + lr;
  const float bv = bias[m * OUTF + o];
#pragma unroll
  for (int j = 0; j < 4; ++j) {
    const int s0 = lg * 4 + j;
    if (s0 < nb) out[(size_t)sid[s0] * OUTF + o] = acc0[j] + bv;
    const int s1 = 16 + lg * 4 + j;
    if (s1 < nb) out[(size_t)sid[s1] * OUTF + o] = acc1[j] + bv;
  }
}

}  // namespace

extern "C" void kernel_launch(void* const* d_in, const int* in_sizes, int n_in,
                              void* d_out, int out_size, void* d_ws, size_t ws_size,
                              hipStream_t stream) {
  const float* x    = (const float*)d_in[0];
  const int*   idx  = (const int*)d_in[1];
  const float* w    = (const float*)d_in[2];
  const float* bias = (const float*)d_in[3];
  float*       out  = (float*)d_out;

  int* cnt = (int*)d_ws;                                          // 64 ints
  unsigned short* bucket = (unsigned short*)((char*)d_ws + 256);  // 64*512 u16

  hipLaunchKernelGGL(scatter_kernel, dim3(NM), dim3(256), 0, stream,
                     idx, cnt, bucket);
  hipLaunchKernelGGL(gemm_kernel, dim3(NM, MAXT, 4), dim3(256), 0, stream,
                     x, w, bias, cnt, bucket, out);
}

// Round 6
// 32.746 us; speedup vs baseline: 2.1275x; 1.0265x over previous
//
#include <hip/hip_runtime.h>

typedef __attribute__((ext_vector_type(8))) short short8;
typedef __attribute__((ext_vector_type(4))) float f32x4;

namespace {

constexpr int NM    = 64;
constexpr int INF   = 256;
constexpr int OUTF  = 256;
constexpr int BATCH = 8192;
constexpr int TS    = 32;    // samples per MFMA tile
constexpr int WIN   = 128;   // sample window per block (4 tiles)
constexpr int NTG   = 2;     // windows: covers n_m <= 256 (mean 128, sd 11 -> 11 sigma)
constexpr int OQ    = 64;    // outputs per block

// RNE f32 -> bf16, software. Inputs are finite.
__device__ inline unsigned short bf16_rne(float f) {
  const unsigned u = __float_as_uint(f);
  return (unsigned short)((u + 0x7FFFu + ((u >> 16) & 1u)) >> 16);
}

// LDS layout of a [rows][256] bf16 tile (512 B/row): element (row,k) at byte
// swz(row, 2k). XOR of bits 4-6 by (row&7) kills the stride-512B b128 bank
// conflict; preserves 8/16B alignment. (R4/R5-verified.)
__device__ inline int swz(int row, int byte_in_row) {
  return row * 512 + (byte_in_row ^ ((row & 7) << 4));
}

__device__ inline void stage4(char* lds, int row, int chunk, float4 v) {
  union { unsigned short s[4]; uint2 u; } p;
  p.s[0] = bf16_rne(v.x);
  p.s[1] = bf16_rne(v.y);
  p.s[2] = bf16_rne(v.z);
  p.s[3] = bf16_rne(v.w);
  *reinterpret_cast<uint2*>(lds + swz(row, chunk * 8)) = p.u;
}

// Single fused dispatch (R5 lesson: each dispatch boundary costs ~11 us).
// Block (m, q, tg): model m, outputs [q*64, +64), samples whose canonical
// rank (sample-id order among idx==m) is in [tg*128, +128).
// Phase 1: deterministic ballot-rank scan of all 8192 indices (no atomics;
// every block of model m computes the identical ranking -> no overlap/gaps).
// Phase 2: stage w quarter to LDS (bf16, swizzled), loop 4 tiles of 32
// samples through one x buffer with the R4-proven mfma_f32_16x16x32_bf16 path.
__global__ __launch_bounds__(256) void fused_kernel(
    const float* __restrict__ x,      // [BATCH][INF]
    const int*   __restrict__ idx,    // [BATCH]
    const float* __restrict__ w,      // [NM][OUTF][INF]
    const float* __restrict__ bias,   // [NM][OUTF]
    float*       __restrict__ out)    // [BATCH][OUTF]
{
  const int m  = blockIdx.x;
  const int q  = blockIdx.y;
  const int tg = blockIdx.z;
  const int win_lo = tg * WIN;

  __shared__ __align__(16) char ws[OQ * 512];  // 32 KB: [64][256] bf16 swizzled
  __shared__ __align__(16) char xs[TS * 512];  // 16 KB: [32][256] bf16 swizzled
  __shared__ int sid[WIN];
  __shared__ int wcnt[4];

  const int tid  = threadIdx.x;
  const int lane = tid & 63;
  const int wid  = tid >> 6;

  // ---- Phase 1: ballot-rank scan. BATCH = 32 * 256 exactly.
  int running = 0;
  for (int i0 = 0; i0 < BATCH; i0 += 256) {
    const int i = i0 + tid;
    const bool match = (idx[i] == m);
    const unsigned long long b = __ballot(match);
    if (lane == 0) wcnt[wid] = __popcll(b);
    __syncthreads();
    int pref = running;
    int tot  = 0;
#pragma unroll
    for (int wv = 0; wv < 4; ++wv) {
      const int c = wcnt[wv];
      if (wv < wid) pref += c;
      tot += c;
    }
    if (match) {
      const int rank = pref + __popcll(b & ((1ULL << lane) - 1ULL));
      const int slot = rank - win_lo;
      if (slot >= 0 && slot < WIN) sid[slot] = i;
    }
    running += tot;
    __syncthreads();
  }
  const int nwin = min(max(running - win_lo, 0), WIN);
  if (nwin == 0) return;  // empty window: skip w staging entirely

  // ---- Phase 2a: stage w quarter. r = tid>>2 (0..63), qq = tid&3.
  {
    const int r  = tid >> 2;
    const int qq = tid & 3;
    const float4* __restrict__ wrow = reinterpret_cast<const float4*>(
        w + ((size_t)m * OUTF + q * OQ + r) * INF);
#pragma unroll
    for (int j = 0; j < 16; ++j) stage4(ws, r, qq * 16 + j, wrow[qq * 16 + j]);
  }

  const int lr = lane & 15;
  const int lg = lane >> 4;
  const int o  = q * OQ + wid * 16 + lr;
  const float bv = bias[m * OUTF + o];

  // ---- Phase 2b: tile loop over the window.
  for (int t = 0; t < WIN / TS; ++t) {
    const int nb = min(TS, nwin - t * TS);
    if (nb <= 0) break;

    __syncthreads();  // ws/sid visible (1st iter); xs safe to overwrite (later)

    // stage x tile: row r = tid>>3 (0..31), c = tid&7 (8 float4 chunks).
    {
      const int r = tid >> 3;
      const int c = tid & 7;
      if (r < nb) {
        const float4* __restrict__ xrow = reinterpret_cast<const float4*>(
            x + (size_t)sid[t * TS + r] * INF);
#pragma unroll
        for (int j = 0; j < 8; ++j) stage4(xs, r, c * 8 + j, xrow[c * 8 + j]);
      } else {
        const float4 z = make_float4(0.f, 0.f, 0.f, 0.f);
#pragma unroll
        for (int j = 0; j < 8; ++j) stage4(xs, r, c * 8 + j, z);
      }
    }
    __syncthreads();

    f32x4 acc0 = {0.f, 0.f, 0.f, 0.f};
    f32x4 acc1 = {0.f, 0.f, 0.f, 0.f};

#pragma unroll
    for (int kc = 0; kc < 8; ++kc) {
      const int kb = kc * 64 + lg * 16;  // byte offset of this lane's 8 bf16
      const short8 a0 = *reinterpret_cast<const short8*>(xs + swz(lr, kb));
      const short8 a1 = *reinterpret_cast<const short8*>(xs + swz(16 + lr, kb));
      const short8 bfr =
          *reinterpret_cast<const short8*>(ws + swz(wid * 16 + lr, kb));
      acc0 = __builtin_amdgcn_mfma_f32_16x16x32_bf16(a0, bfr, acc0, 0, 0, 0);
      acc1 = __builtin_amdgcn_mfma_f32_16x16x32_bf16(a1, bfr, acc1, 0, 0, 0);
    }

    // epilogue: bias + guarded scatter-store (D: col=lane&15, row=4*lg+j).
#pragma unroll
    for (int j = 0; j < 4; ++j) {
      const int s0 = lg * 4 + j;
      if (s0 < nb) out[(size_t)sid[t * TS + s0] * OUTF + o] = acc0[j] + bv;
      const int s1 = 16 + lg * 4 + j;
      if (s1 < nb) out[(size_t)sid[t * TS + s1] * OUTF + o] = acc1[j] + bv;
    }
  }
}

}  // namespace

extern "C" void kernel_launch(void* const* d_in, const int* in_sizes, int n_in,
                              void* d_out, int out_size, void* d_ws, size_t ws_size,
                              hipStream_t stream) {
  const float* x    = (const float*)d_in[0];
  const int*   idx  = (const int*)d_in[1];
  const float* w    = (const float*)d_in[2];
  const float* bias = (const float*)d_in[3];
  float*       out  = (float*)d_out;

  hipLaunchKernelGGL(fused_kernel, dim3(NM, 4, NTG), dim3(256), 0, stream,
                     x, idx, w, bias, out);
}

// Round 7
// 29.434 us; speedup vs baseline: 2.3669x; 1.1125x over previous
//
#include <hip/hip_runtime.h>

typedef __attribute__((ext_vector_type(8))) short short8;
typedef __attribute__((ext_vector_type(4))) float f32x4;

namespace {

constexpr int NM    = 64;
constexpr int INF   = 256;
constexpr int OUTF  = 256;
constexpr int BATCH = 8192;
constexpr int MAXN  = 512;   // bucket capacity
constexpr int TS    = 32;    // samples per MFMA tile
constexpr int MAXT  = 8;     // covers n_m <= 256 (mean 128, sd 11.25 -> 11 sigma)
constexpr int OQ    = 64;    // outputs per block

constexpr int SCAT_B  = 64;   // scatter blocks (one per model)
constexpr int WCONV_B = 256;  // w f32->bf16 convert blocks
constexpr int XCONV_B = 128;  // x f32->bf16 convert blocks

// RNE f32 -> bf16 (R4-proven). Inputs finite.
__device__ inline unsigned short bf16_rne(float f) {
  const unsigned u = __float_as_uint(f);
  return (unsigned short)((u + 0x7FFFu + ((u >> 16) & 1u)) >> 16);
}
__device__ inline unsigned pack2(float a, float b) {
  return (unsigned)bf16_rne(a) | ((unsigned)bf16_rne(b) << 16);
}

// LDS layout of a [rows][256] bf16 tile (512 B/row): element (row,k) at byte
// swz(row, 2k). XOR of bits 4-6 by (row&7) kills the stride-512B b128 bank
// conflict; preserves 16B alignment. (R4/R5/R6-verified.)
__device__ inline int swz(int row, int byte_in_row) {
  return row * 512 + (byte_in_row ^ ((row & 7) << 4));
}

// ---- Kernel 1: prep. Three block roles in one dispatch:
//   b <  64           : barrier-free scatter for model b (no atomics at all;
//                       per-wave ballot-rank over a 2048-index chunk, then a
//                       single barrier + prefix over 4 wave counts).
//   64 <= b < 320     : w f32->bf16 convert (grid-exact, coalesced).
//   320 <= b < 448    : x f32->bf16 convert.
__global__ __launch_bounds__(256) void prep_kernel(
    const float* __restrict__ x, const int* __restrict__ idx,
    const float* __restrict__ w,
    int* __restrict__ cnt, unsigned short* __restrict__ bucket,
    unsigned short* __restrict__ wbf, unsigned short* __restrict__ xbf)
{
  const int b = blockIdx.x;
  const int tid = threadIdx.x;

  if (b < SCAT_B) {
    __shared__ unsigned short stage[4][BATCH / 4];  // 16 KB; cannot overflow
    __shared__ int wtot[4];
    const int m = b;
    const int wv = tid >> 6, lane = tid & 63;
    const unsigned long long lt = (1ULL << lane) - 1ULL;
    const int base = wv * (BATCH / 4);
    int c = 0;  // wave-uniform running count
#pragma unroll 4
    for (int it = 0; it < BATCH / 4 / 64; ++it) {
      const int i = base + it * 64 + lane;
      const bool match = (idx[i] == m);
      const unsigned long long bl = __ballot(match);
      if (match) stage[wv][c + __popcll(bl & lt)] = (unsigned short)i;
      c += __popcll(bl);
    }
    if (lane == 0) wtot[wv] = c;
    __syncthreads();
    int off = 0, tot = 0;
#pragma unroll
    for (int v = 0; v < 4; ++v) {
      const int tv = wtot[v];
      if (v < wv) off += tv;
      tot += tv;
    }
    for (int r = lane; r < c; r += 64) {
      const int d = off + r;
      if (d < MAXN) bucket[m * MAXN + d] = stage[wv][r];
    }
    if (tid == 0) cnt[m] = min(tot, MAXN);
  } else if (b < SCAT_B + WCONV_B) {
    // 256 blocks * 256 thr * 8 iters * 8 elems = 4,194,304 = NM*OUTF*INF exact
    const int g0 = (b - SCAT_B) * 256 + tid;
#pragma unroll
    for (int it = 0; it < 8; ++it) {
      const int g = it * (WCONV_B * 256) + g0;  // 8-element group
      const float4 a  = reinterpret_cast<const float4*>(w)[g * 2];
      const float4 b2 = reinterpret_cast<const float4*>(w)[g * 2 + 1];
      uint4 p;
      p.x = pack2(a.x, a.y);  p.y = pack2(a.z, a.w);
      p.z = pack2(b2.x, b2.y); p.w = pack2(b2.z, b2.w);
      reinterpret_cast<uint4*>(wbf)[g] = p;
    }
  } else {
    // 128 blocks * 256 thr * 8 iters * 8 elems = 2,097,152 = BATCH*INF exact
    const int g0 = (b - SCAT_B - WCONV_B) * 256 + tid;
#pragma unroll
    for (int it = 0; it < 8; ++it) {
      const int g = it * (XCONV_B * 256) + g0;
      const float4 a  = reinterpret_cast<const float4*>(x)[g * 2];
      const float4 b2 = reinterpret_cast<const float4*>(x)[g * 2 + 1];
      uint4 p;
      p.x = pack2(a.x, a.y);  p.y = pack2(a.z, a.w);
      p.z = pack2(b2.x, b2.y); p.w = pack2(b2.z, b2.w);
      reinterpret_cast<uint4*>(xbf)[g] = p;
    }
  }
}

// ---- Kernel 2: per (model, 32-sample tile, 64-output quarter) MFMA tile.
// Staging is now pure vector moves (bf16 pre-converted): 8 uint4 for w,
// 4 uint4 for x, swizzled ds_write_b128. MFMA core is R4/R5-proven.
__global__ __launch_bounds__(256) void gemm_kernel(
    const unsigned short* __restrict__ xbf,    // [BATCH][INF] bf16
    const unsigned short* __restrict__ wbf,    // [NM][OUTF][INF] bf16
    const float* __restrict__ bias,            // [NM][OUTF]
    const int* __restrict__ cnt,               // [NM]
    const unsigned short* __restrict__ bucket, // [NM][MAXN]
    float* __restrict__ out)                   // [BATCH][OUTF]
{
  const int m = blockIdx.x;
  const int t = blockIdx.y;
  const int q = blockIdx.z;
  const int n = min(cnt[m], MAXN);
  const int base = t * TS;
  if (base >= n) return;
  const int nb = min(TS, n - base);

  __shared__ __align__(16) char ws[OQ * 512];  // 32 KB bf16, swizzled
  __shared__ __align__(16) char xs[TS * 512];  // 16 KB bf16, swizzled
  __shared__ int sid[TS];

  const int tid = threadIdx.x;

  if (tid < TS) sid[tid] = (tid < nb) ? (int)bucket[m * MAXN + base + tid] : 0;

  // --- stage w quarter: 2048 granules of 16B, linear global reads.
  {
    const size_t wq = ((size_t)m * OUTF + (size_t)q * OQ) * INF;  // in ushorts
    const uint4* __restrict__ src = reinterpret_cast<const uint4*>(wbf + wq);
    uint4 v[8];
#pragma unroll
    for (int g8 = 0; g8 < 8; ++g8) v[g8] = src[g8 * 256 + tid];
#pragma unroll
    for (int g8 = 0; g8 < 8; ++g8) {
      const int G = g8 * 256 + tid;
      const int row = G >> 5;            // 32 granules per 512B row
      const int cb  = (G & 31) * 16;
      *reinterpret_cast<uint4*>(ws + swz(row, cb)) = v[g8];
    }
  }
  __syncthreads();  // sid + ws visible

  // --- stage x tile: row r = tid>>3, seg = tid&7 (4 granules each).
  {
    const int r = tid >> 3;
    const int seg = tid & 7;
    if (r < nb) {
      const uint4* __restrict__ src =
          reinterpret_cast<const uint4*>(xbf + (size_t)sid[r] * INF);
      uint4 v[4];
#pragma unroll
      for (int j = 0; j < 4; ++j) v[j] = src[seg * 4 + j];
#pragma unroll
      for (int j = 0; j < 4; ++j)
        *reinterpret_cast<uint4*>(xs + swz(r, seg * 64 + j * 16)) = v[j];
    } else {
      const uint4 z = {0u, 0u, 0u, 0u};
#pragma unroll
      for (int j = 0; j < 4; ++j)
        *reinterpret_cast<uint4*>(xs + swz(r, seg * 64 + j * 16)) = z;
    }
  }
  __syncthreads();

  const int wid = tid >> 6;
  const int l   = tid & 63;
  const int lr  = l & 15;
  const int lg  = l >> 4;

  f32x4 acc0 = {0.f, 0.f, 0.f, 0.f};
  f32x4 acc1 = {0.f, 0.f, 0.f, 0.f};

#pragma unroll
  for (int kc = 0; kc < 8; ++kc) {
    const int kb = kc * 64 + lg * 16;
    const short8 a0 = *reinterpret_cast<const short8*>(xs + swz(lr, kb));
    const short8 a1 = *reinterpret_cast<const short8*>(xs + swz(16 + lr, kb));
    const short8 bfr =
        *reinterpret_cast<const short8*>(ws + swz(wid * 16 + lr, kb));
    acc0 = __builtin_amdgcn_mfma_f32_16x16x32_bf16(a0, bfr, acc0, 0, 0, 0);
    acc1 = __builtin_amdgcn_mfma_f32_16x16x32_bf16(a1, bfr, acc1, 0, 0, 0);
  }

  // --- epilogue: bias + guarded scatter-store (D: col=lane&15, row=4*lg+j).
  const int o = q * OQ + wid * 16 + lr;
  const float bv = bias[m * OUTF + o];
#pragma unroll
  for (int j = 0; j < 4; ++j) {
    const int s0 = lg * 4 + j;
    if (s0 < nb) out[(size_t)sid[s0] * OUTF + o] = acc0[j] + bv;
    const int s1 = 16 + lg * 4 + j;
    if (s1 < nb) out[(size_t)sid[s1] * OUTF + o] = acc1[j] + bv;
  }
}

}  // namespace

extern "C" void kernel_launch(void* const* d_in, const int* in_sizes, int n_in,
                              void* d_out, int out_size, void* d_ws, size_t ws_size,
                              hipStream_t stream) {
  const float* x    = (const float*)d_in[0];
  const int*   idx  = (const int*)d_in[1];
  const float* w    = (const float*)d_in[2];
  const float* bias = (const float*)d_in[3];
  float*       out  = (float*)d_out;

  // d_ws layout (all 16B-aligned): cnt[64] | bucket[64*512 u16] | w_bf16 | x_bf16
  int* cnt = (int*)d_ws;
  unsigned short* bucket = (unsigned short*)((char*)d_ws + 256);
  unsigned short* wbf = (unsigned short*)((char*)d_ws + 256 + 65536);
  unsigned short* xbf = (unsigned short*)((char*)d_ws + 256 + 65536 +
                                          (size_t)NM * OUTF * INF * 2);

  hipLaunchKernelGGL(prep_kernel, dim3(SCAT_B + WCONV_B + XCONV_B), dim3(256),
                     0, stream, x, idx, w, cnt, bucket, wbf, xbf);
  hipLaunchKernelGGL(gemm_kernel, dim3(NM, MAXT, 4), dim3(256), 0, stream,
                     xbf, wbf, bias, cnt, bucket, out);
}